// Round 7
// baseline (505.867 us; speedup 1.0000x reference)
//
#include <hip/hip_runtime.h>
#include <hip/hip_bf16.h>
#include <math.h>

#define SHIFT 20.0f   // softmax shift-invariance: exp(sc-SHIFT) exact vs ref
#define T_PER 16
#define TILE (256 * T_PER)

#define REP16(M) M(0) M(1) M(2) M(3) M(4) M(5) M(6) M(7) \
                 M(8) M(9) M(10) M(11) M(12) M(13) M(14) M(15)

// ---------- zero two regions ----------
__global__ void zero2_kernel(float* p1, size_t n1, float* p2, size_t n2) {
    size_t i = (size_t)blockIdx.x * blockDim.x + threadIdx.x;
    size_t stride = (size_t)gridDim.x * blockDim.x;
    for (size_t j = i; j < n1; j += stride) p1[j] = 0.f;
    for (size_t j = i; j < n2; j += stride) p2[j] = 0.f;
}

// ---------- CSR build: histogram of in-degree (self loops implicit) ----------
__global__ void hist_kernel(const int* __restrict__ edst, int* __restrict__ cnt,
                            int nE, int nN) {
    int i = blockIdx.x * blockDim.x + threadIdx.x;
    int stride = gridDim.x * blockDim.x;
    int tot = nE + nN;
    for (int e = i; e < tot; e += stride) {
        int d = (e < nE) ? edst[e] : (e - nE);
        atomicAdd(&cnt[d], 1);
    }
}

// ---------- CSR build: per-chunk sums (256 blocks) ----------
__global__ void scan_chunk_sum_kernel(const int* __restrict__ cnt,
                                      int* __restrict__ bsum, int nN, int chunk) {
    __shared__ int red[256];
    int b = blockIdx.x, t = threadIdx.x;
    int lo = b * chunk, hi = min(lo + chunk, nN);
    int s = 0;
    for (int i = lo + t; i < hi; i += 256) s += cnt[i];
    red[t] = s;
    __syncthreads();
    for (int off = 128; off > 0; off >>= 1) {
        if (t < off) red[t] += red[t + off];
        __syncthreads();
    }
    if (t == 0) bsum[b] = red[0];
}

// ---------- CSR build: exclusive scan of 256 chunk sums (1 block) ----------
__global__ void scan_bsum_kernel(const int* __restrict__ bsum,
                                 int* __restrict__ boff, int B) {
    __shared__ int sh[256];
    int t = threadIdx.x;
    int orig = (t < B) ? bsum[t] : 0;
    sh[t] = orig;
    __syncthreads();
    for (int off = 1; off < 256; off <<= 1) {
        int u = (t >= off) ? sh[t - off] : 0;
        __syncthreads();
        sh[t] += u;
        __syncthreads();
    }
    if (t < B) boff[t] = sh[t] - orig;
}

// ---------- CSR build: scan each chunk, write rowptr ----------
__global__ void scan_write_kernel(const int* __restrict__ cnt,
                                  const int* __restrict__ boff,
                                  int* __restrict__ rowptr,
                                  int nN, int chunk) {
    __shared__ int sh[256];
    __shared__ int run;
    int b = blockIdx.x, t = threadIdx.x;
    int lo = b * chunk, hi = min(lo + chunk, nN);
    if (t == 0) run = boff[b];
    __syncthreads();
    for (int base = lo; base < hi; base += 256) {
        int i = base + t;
        int v = (i < hi) ? cnt[i] : 0;
        sh[t] = v;
        __syncthreads();
        for (int off = 1; off < 256; off <<= 1) {
            int u = (t >= off) ? sh[t - off] : 0;
            __syncthreads();
            sh[t] += u;
            __syncthreads();
        }
        int excl = sh[t] - v + run;
        if (i < hi) rowptr[i] = excl;
        int tilesum = sh[255];
        __syncthreads();
        if (t == 0) run += tilesum;
        __syncthreads();
    }
    if (t == 0 && lo < nN && hi == nN) rowptr[nN] = run;
}

// ---------- coarse-bucket cursor init (512-node buckets, 64B-padded) ----------
__global__ void init_bcur_kernel(const int* __restrict__ rowptr,
                                 int* __restrict__ bcur, int K2, int nN) {
    int b = blockIdx.x * blockDim.x + threadIdx.x;
    if (b < K2) bcur[b * 16] = rowptr[min(b * 512, nN)];
}

// ---------- pass A: tile-local multisplit into per-(tile,bucket) segments ----
__global__ __launch_bounds__(256) void multisplit_kernel(
    const int* __restrict__ esrc, const int* __restrict__ edst,
    int* __restrict__ bcur, unsigned* __restrict__ pairbuf,
    int nE, int nN, int K2, int nTiles)
{
    __shared__ int lhist[256];
    __shared__ int lbase[256];
    int t = threadIdx.x;
    int tot = nE + nN;

    for (int tile = blockIdx.x; tile < nTiles; tile += gridDim.x) {
        int base = tile * TILE;
        if (t < K2) lhist[t] = 0;
        __syncthreads();

        unsigned pk[T_PER];
        int loc[T_PER];
        #pragma unroll
        for (int i = 0; i < T_PER; i++) {
            int e = base + t + i * 256;
            if (e < tot) {
                int s = (e < nE) ? esrc[e] : (e - nE);
                int d = (e < nE) ? edst[e] : (e - nE);
                int b = d >> 9;
                pk[i] = ((unsigned)s << 9) | (unsigned)(d & 511);
                int idx = atomicAdd(&lhist[b], 1);     // LDS atomic
                loc[i] = (b << 20) | idx;
            } else loc[i] = -1;
        }
        __syncthreads();
        if (t < K2) {
            int c = lhist[t];
            lbase[t] = (c > 0) ? atomicAdd(&bcur[t * 16], c) : 0;
        }
        __syncthreads();
        #pragma unroll
        for (int i = 0; i < T_PER; i++) {
            if (loc[i] >= 0)
                pairbuf[lbase[loc[i] >> 20] + (loc[i] & 0xFFFFF)] = pk[i];
        }
        __syncthreads();
    }
}

// ---------- pass B: per-bucket local scatter into contiguous CSR window ----
__global__ __launch_bounds__(256) void local_scatter_kernel(
    const unsigned* __restrict__ pairbuf, const int* __restrict__ rowptr,
    int* __restrict__ csr_src, int nN)
{
    __shared__ int cur[512];
    int d0 = blockIdx.x * 512;
    int nd = min(512, nN - d0);
    for (int i = threadIdx.x; i < nd; i += 256) cur[i] = rowptr[d0 + i];
    __syncthreads();
    int lo = rowptr[d0];
    int hi = rowptr[min(d0 + 512, nN)];
    for (int j = lo + (int)threadIdx.x; j < hi; j += 256) {
        unsigned w = pairbuf[j];
        int pos = atomicAdd(&cur[w & 511u], 1);
        csr_src[pos] = (int)(w >> 9);
    }
}

// ---------- h = X @ W (64x64) + attention dots; THREAD per node -------------
// NAMED float4 accumulators (macro-expanded) -> guaranteed VGPRs, no scratch.
__global__ __launch_bounds__(256) void gemm_att_kernel(
    const float* __restrict__ X, const float* __restrict__ W,
    const float* __restrict__ a_s, const float* __restrict__ a_d,
    float* __restrict__ Hout, float* __restrict__ als, float* __restrict__ ald,
    int nN)
{
    int n = blockIdx.x * blockDim.x + threadIdx.x;
    if (n >= nN) return;
    const float4* x4 = (const float4*)(X + (size_t)n * 64);

#define DECLA(i) float4 a##i = make_float4(0.f, 0.f, 0.f, 0.f);
    REP16(DECLA)
#undef DECLA

    #pragma unroll 4
    for (int i = 0; i < 16; i++) {
        float4 xv = x4[i];                                // per-thread load
        const float4* w0 = (const float4*)(W + (i * 4 + 0) * 64);  // uniform
        const float4* w1 = (const float4*)(W + (i * 4 + 1) * 64);
        const float4* w2 = (const float4*)(W + (i * 4 + 2) * 64);
        const float4* w3 = (const float4*)(W + (i * 4 + 3) * 64);
#define FMAS(q) { \
        float4 u0 = w0[q], u1 = w1[q], u2 = w2[q], u3 = w3[q]; \
        a##q.x = fmaf(xv.x, u0.x, a##q.x); a##q.y = fmaf(xv.x, u0.y, a##q.y); \
        a##q.z = fmaf(xv.x, u0.z, a##q.z); a##q.w = fmaf(xv.x, u0.w, a##q.w); \
        a##q.x = fmaf(xv.y, u1.x, a##q.x); a##q.y = fmaf(xv.y, u1.y, a##q.y); \
        a##q.z = fmaf(xv.y, u1.z, a##q.z); a##q.w = fmaf(xv.y, u1.w, a##q.w); \
        a##q.x = fmaf(xv.z, u2.x, a##q.x); a##q.y = fmaf(xv.z, u2.y, a##q.y); \
        a##q.z = fmaf(xv.z, u2.z, a##q.z); a##q.w = fmaf(xv.z, u2.w, a##q.w); \
        a##q.x = fmaf(xv.w, u3.x, a##q.x); a##q.y = fmaf(xv.w, u3.y, a##q.y); \
        a##q.z = fmaf(xv.w, u3.z, a##q.z); a##q.w = fmaf(xv.w, u3.w, a##q.w); }
        REP16(FMAS)
#undef FMAS
    }

    float s1 = 0.f, s2 = 0.f;
    const float4* as4 = (const float4*)a_s;
    const float4* ad4 = (const float4*)a_d;
#define DOTS(i) { float4 u = as4[i], v = ad4[i]; \
    s1 = fmaf(a##i.x, u.x, fmaf(a##i.y, u.y, fmaf(a##i.z, u.z, fmaf(a##i.w, u.w, s1)))); \
    s2 = fmaf(a##i.x, v.x, fmaf(a##i.y, v.y, fmaf(a##i.z, v.z, fmaf(a##i.w, v.w, s2)))); }
    REP16(DOTS)
#undef DOTS
    als[n] = s1;
    ald[n] = s2;

    float4* ho = (float4*)(Hout + (size_t)n * 64);
#define STH(i) ho[i] = a##i;
    REP16(STH)
#undef STH
}

// ---------- single-pass pull aggregation (fixed softmax shift) ----------
__global__ __launch_bounds__(256) void pull_kernel(
    const int* __restrict__ csr_src, const int* __restrict__ rowptr,
    const float* __restrict__ Hin,
    const float* __restrict__ als, const float* __restrict__ ald,
    const float* __restrict__ bias, float* __restrict__ out, int nN)
{
    int lane = threadIdx.x & 63;
    int wid  = (blockIdx.x * blockDim.x + threadIdx.x) >> 6;
    int nw   = (gridDim.x * blockDim.x) >> 6;
    float bl = bias[lane];

    for (int d = wid; d < nN; d += nw) {
        int s0 = rowptr[d], s1 = rowptr[d + 1];
        float aldd = ald[d];
        float acc = 0.f, den = 0.f;
        int j = s0;
        for (; j + 3 < s1; j += 4) {
            int sA = csr_src[j], sB = csr_src[j + 1];
            int sC = csr_src[j + 2], sD = csr_src[j + 3];
            float scA = als[sA] + aldd, scB = als[sB] + aldd;
            float scC = als[sC] + aldd, scD = als[sD] + aldd;
            float hA = Hin[(size_t)sA * 64 + lane];
            float hB = Hin[(size_t)sB * 64 + lane];
            float hC = Hin[(size_t)sC * 64 + lane];
            float hD = Hin[(size_t)sD * 64 + lane];
            scA = (scA > 0.f) ? scA : 0.2f * scA;
            scB = (scB > 0.f) ? scB : 0.2f * scB;
            scC = (scC > 0.f) ? scC : 0.2f * scC;
            scD = (scD > 0.f) ? scD : 0.2f * scD;
            float exA = __expf(scA - SHIFT), exB = __expf(scB - SHIFT);
            float exC = __expf(scC - SHIFT), exD = __expf(scD - SHIFT);
            den += (exA + exB) + (exC + exD);
            acc = fmaf(exA, hA, acc);
            acc = fmaf(exB, hB, acc);
            acc = fmaf(exC, hC, acc);
            acc = fmaf(exD, hD, acc);
        }
        for (; j < s1; j++) {
            int s = csr_src[j];
            float sc = als[s] + aldd;
            sc = (sc > 0.f) ? sc : 0.2f * sc;
            float ex = __expf(sc - SHIFT);
            den += ex;
            acc = fmaf(ex, Hin[(size_t)s * 64 + lane], acc);
        }
        float v = acc / den + bl;
        out[(size_t)d * 64 + lane] = (v > 0.f) ? v : expm1f(v);
    }
}

// ---------- head: THREAD per node; named-register MLP; segmented pool -------
__global__ __launch_bounds__(256) void mlp_pool_kernel(
    const float* __restrict__ Hin,
    const float* __restrict__ mw1, const float* __restrict__ mb1,
    const float* __restrict__ mw2, const float* __restrict__ mb2,
    const int* __restrict__ batch, float* __restrict__ out, int nN)
{
    int n = blockIdx.x * blockDim.x + threadIdx.x;
    int lane = threadIdx.x & 63;
    bool valid = (n < nN);
    int nc = valid ? n : (nN - 1);
    int g = batch[nc];

    const float4* x4 = (const float4*)(Hin + (size_t)nc * 64);
    const float4* mb14 = (const float4*)mb1;

#define DECLA(i) float4 a##i = mb14[i];
    REP16(DECLA)
#undef DECLA

    #pragma unroll 4
    for (int i = 0; i < 16; i++) {
        float4 xv = x4[i];
        const float4* w0 = (const float4*)(mw1 + (i * 4 + 0) * 64);
        const float4* w1 = (const float4*)(mw1 + (i * 4 + 1) * 64);
        const float4* w2 = (const float4*)(mw1 + (i * 4 + 2) * 64);
        const float4* w3 = (const float4*)(mw1 + (i * 4 + 3) * 64);
#define FMAS(q) { \
        float4 u0 = w0[q], u1 = w1[q], u2 = w2[q], u3 = w3[q]; \
        a##q.x = fmaf(xv.x, u0.x, a##q.x); a##q.y = fmaf(xv.x, u0.y, a##q.y); \
        a##q.z = fmaf(xv.x, u0.z, a##q.z); a##q.w = fmaf(xv.x, u0.w, a##q.w); \
        a##q.x = fmaf(xv.y, u1.x, a##q.x); a##q.y = fmaf(xv.y, u1.y, a##q.y); \
        a##q.z = fmaf(xv.y, u1.z, a##q.z); a##q.w = fmaf(xv.y, u1.w, a##q.w); \
        a##q.x = fmaf(xv.z, u2.x, a##q.x); a##q.y = fmaf(xv.z, u2.y, a##q.y); \
        a##q.z = fmaf(xv.z, u2.z, a##q.z); a##q.w = fmaf(xv.z, u2.w, a##q.w); \
        a##q.x = fmaf(xv.w, u3.x, a##q.x); a##q.y = fmaf(xv.w, u3.y, a##q.y); \
        a##q.z = fmaf(xv.w, u3.z, a##q.z); a##q.w = fmaf(xv.w, u3.w, a##q.w); }
        REP16(FMAS)
#undef FMAS
    }

    float o0 = mb2[0], o1 = mb2[1], o2 = mb2[2], o3 = mb2[3], o4 = mb2[4];
    float o5 = mb2[5], o6 = mb2[6], o7 = mb2[7], o8 = mb2[8], o9 = mb2[9];

#define L2C(i, C, J) { float r = fmaxf(a##i.C, 0.f); \
    const float* wr = mw2 + ((i) * 4 + (J)) * 10; \
    o0 = fmaf(r, wr[0], o0); o1 = fmaf(r, wr[1], o1); o2 = fmaf(r, wr[2], o2); \
    o3 = fmaf(r, wr[3], o3); o4 = fmaf(r, wr[4], o4); o5 = fmaf(r, wr[5], o5); \
    o6 = fmaf(r, wr[6], o6); o7 = fmaf(r, wr[7], o7); o8 = fmaf(r, wr[8], o8); \
    o9 = fmaf(r, wr[9], o9); }
#define L2(i) L2C(i, x, 0) L2C(i, y, 1) L2C(i, z, 2) L2C(i, w, 3)
    REP16(L2)
#undef L2
#undef L2C

    if (!valid) { o0=o1=o2=o3=o4=o5=o6=o7=o8=o9=0.f; }

    int g0 = __shfl(g, 0);
    if (__all(g == g0)) {
#define RED(J, oJ) { float v = oJ; \
        v += __shfl_xor(v, 32); v += __shfl_xor(v, 16); v += __shfl_xor(v, 8); \
        v += __shfl_xor(v, 4);  v += __shfl_xor(v, 2);  v += __shfl_xor(v, 1); \
        if (lane == J) atomicAdd(&out[(size_t)g0 * 10 + J], v); }
        RED(0, o0) RED(1, o1) RED(2, o2) RED(3, o3) RED(4, o4)
        RED(5, o5) RED(6, o6) RED(7, o7) RED(8, o8) RED(9, o9)
#undef RED
    } else {
        atomicAdd(&out[(size_t)g * 10 + 0], o0);
        atomicAdd(&out[(size_t)g * 10 + 1], o1);
        atomicAdd(&out[(size_t)g * 10 + 2], o2);
        atomicAdd(&out[(size_t)g * 10 + 3], o3);
        atomicAdd(&out[(size_t)g * 10 + 4], o4);
        atomicAdd(&out[(size_t)g * 10 + 5], o5);
        atomicAdd(&out[(size_t)g * 10 + 6], o6);
        atomicAdd(&out[(size_t)g * 10 + 7], o7);
        atomicAdd(&out[(size_t)g * 10 + 8], o8);
        atomicAdd(&out[(size_t)g * 10 + 9], o9);
    }
}

extern "C" void kernel_launch(void* const* d_in, const int* in_sizes, int n_in,
                              void* d_out, int out_size, void* d_ws, size_t ws_size,
                              hipStream_t stream)
{
    const float* x   = (const float*)d_in[0];
    const int*  eidx = (const int*)d_in[1];
    const int* batch = (const int*)d_in[2];
    const float* W1  = (const float*)d_in[3];
    const float* as1 = (const float*)d_in[4];
    const float* ad1 = (const float*)d_in[5];
    const float* b1  = (const float*)d_in[6];
    const float* W2  = (const float*)d_in[7];
    const float* as2 = (const float*)d_in[8];
    const float* ad2 = (const float*)d_in[9];
    const float* b2  = (const float*)d_in[10];
    const float* mw1 = (const float*)d_in[11];
    const float* mb1 = (const float*)d_in[12];
    const float* mw2 = (const float*)d_in[13];
    const float* mb2 = (const float*)d_in[14];
    float* out = (float*)d_out;

    int nN = in_sizes[0] / 64;
    int nE = in_sizes[1] / 2;
    int tot = nE + nN;
    int K2 = (nN + 511) >> 9;        // 512-node coarse buckets (<=256)
    const int* esrc = eidx;
    const int* edst = eidx + nE;

    // ---- workspace layout ----
    float* ws = (float*)d_ws;
    size_t NF = (size_t)nN * 64;
    float* bufA   = ws;                          // pairbuf during CSR build; elu1/elu2 after
    float* bufB   = ws + NF;                     // h1 / h2
    float* als    = ws + 2 * NF;
    float* ald    = als + nN;
    int* cnt      = (int*)(ald + nN);            // [nN]
    int* rowptr   = cnt + nN;                    // [nN+1]
    int* csr_src  = rowptr + nN + 1;             // [tot]
    int* bsum     = csr_src + tot;               // [256]
    int* boff     = bsum + 256;                  // [256]
    int* bcur     = boff + 256;                  // [K2*16] (64B-padded cursors)
    unsigned* pairbuf = (unsigned*)bufA;         // [tot], aliased (dead after CSR build)

    dim3 blk(256);
    const int B = 256;
    int chunk = (nN + B - 1) / B;
    int ngrid = (nN + 255) / 256;
    int nTiles = (tot + TILE - 1) / TILE;

    // ---- CSR build (structure shared by both layers) ----
    zero2_kernel<<<512, blk, 0, stream>>>((float*)cnt, (size_t)nN,
                                          out, (size_t)out_size);
    hist_kernel<<<2048, blk, 0, stream>>>(edst, cnt, nE, nN);
    scan_chunk_sum_kernel<<<B, blk, 0, stream>>>(cnt, bsum, nN, chunk);
    scan_bsum_kernel<<<1, blk, 0, stream>>>(bsum, boff, B);
    scan_write_kernel<<<B, blk, 0, stream>>>(cnt, boff, rowptr, nN, chunk);
    init_bcur_kernel<<<(K2 + 255) / 256, blk, 0, stream>>>(rowptr, bcur, K2, nN);
    multisplit_kernel<<<nTiles, blk, 0, stream>>>(esrc, edst, bcur, pairbuf,
                                                  nE, nN, K2, nTiles);
    local_scatter_kernel<<<K2, blk, 0, stream>>>(pairbuf, rowptr, csr_src, nN);

    // ---- layer 1 ----
    gemm_att_kernel<<<ngrid, blk, 0, stream>>>(x, W1, as1, ad1, bufB, als, ald, nN);
    pull_kernel<<<2048, blk, 0, stream>>>(csr_src, rowptr, bufB, als, ald, b1,
                                          bufA, nN);
    // ---- layer 2 ----
    gemm_att_kernel<<<ngrid, blk, 0, stream>>>(bufA, W2, as2, ad2, bufB, als, ald, nN);
    pull_kernel<<<2048, blk, 0, stream>>>(csr_src, rowptr, bufB, als, ald, b2,
                                          bufA, nN);

    // ---- MLP head + global_add_pool ----
    mlp_pool_kernel<<<ngrid, blk, 0, stream>>>(bufA, mw1, mb1, mw2, mb2, batch,
                                               out, nN);
}